// Round 1
// baseline (615.507 us; speedup 1.0000x reference)
//
#include <hip/hip_runtime.h>
#include <hip/hip_bf16.h>
#include <math.h>

#define Bz 64
#define Sz 512
#define Hz 768
#define Nz 128
#define Ez 1024
#define GHz 128
#define FHz 256
#define Lz 2
#define BNz (Bz * Nz)          // 8192

// ---------------- Kernel 1: gate = sigmoid(lh . wr + br); atomic scatter of gated rows ----------------
__global__ void k_gate_scatter(const float* __restrict__ lh, const int* __restrict__ submap,
                               const float* __restrict__ wr, const float* __restrict__ br,
                               float* __restrict__ sums, float* __restrict__ cnts) {
    int row = blockIdx.x;                 // 0 .. B*S-1
    int tid = threadIdx.x;                // 256 threads
    const float* x = lh + (size_t)row * Hz;
    float v0 = x[tid], v1 = x[tid + 256], v2 = x[tid + 512];
    float p = v0 * wr[tid] + v1 * wr[tid + 256] + v2 * wr[tid + 512];
    // wave-64 reduce
    #pragma unroll
    for (int off = 32; off > 0; off >>= 1) p += __shfl_down(p, off);
    __shared__ float wsum[4];
    __shared__ float gate_s;
    int lane = tid & 63, wid = tid >> 6;
    if (lane == 0) wsum[wid] = p;
    __syncthreads();
    if (tid == 0) {
        float z = wsum[0] + wsum[1] + wsum[2] + wsum[3] + br[0];
        gate_s = 1.0f / (1.0f + expf(-z));
    }
    __syncthreads();
    float g = gate_s;
    int b = row >> 9;                     // row / S
    int seg = b * Nz + submap[row];
    float* dstp = sums + (size_t)seg * Hz;
    atomicAdd(dstp + tid,       v0 * g);
    atomicAdd(dstp + tid + 256, v1 * g);
    atomicAdd(dstp + tid + 512, v2 * g);
    if (tid == 0) atomicAdd(cnts + seg, 1.0f);
}

// ---------------- Kernel 2: degree from edges (dst side) ----------------
__global__ void k_deg(const int* __restrict__ ei, float* __restrict__ deg) {
    int idx = blockIdx.x * 256 + threadIdx.x;   // 0 .. B*E-1
    if (idx >= Bz * Ez) return;
    int b = idx >> 10;                          // / E
    int e = idx & (Ez - 1);
    int dst = ei[b * 2 * Ez + Ez + e];
    atomicAdd(deg + b * Nz + dst, 1.0f);
}

// ---------------- Kernel 3: dinv = rsqrt(deg_edges + 1 [self loop]) ----------------
__global__ void k_dinv(float* __restrict__ deg) {
    int i = blockIdx.x * 256 + threadIdx.x;
    if (i < BNz) deg[i] = rsqrtf(deg[i] + 1.0f);
}

// ---------------- Kernel 4: node_feats = sums / max(cnts,1)  (in place) ----------------
__global__ void k_finalize(float* __restrict__ sums, const float* __restrict__ cnts) {
    int row = blockIdx.x;                 // 0..BN-1
    int tid = threadIdx.x;                // 256
    float inv = 1.0f / fmaxf(cnts[row], 1.0f);
    float* p = sums + (size_t)row * Hz;
    p[tid] *= inv; p[tid + 256] *= inv; p[tid + 512] *= inv;
}

// ---------------- GEMM: C(BN x 128) = A(BN x K) @ W(K x 128), f32 vector ALU ----------------
template <int K>
__global__ void k_gemm(const float* __restrict__ A, const float* __restrict__ W,
                       float* __restrict__ C) {
    __shared__ float As[64][65];          // 64 rows x 64 k  (+1 pad)
    __shared__ float Ws[64][128];         // 64 k x 128 cols
    int block_row = blockIdx.x * 64;
    int tid = threadIdx.x;                // 256
    int tx = tid & 15;                    // col group: cols tx + 16*c
    int ty = tid >> 4;                    // row group: rows ty*4 + r
    float acc[4][8];
    #pragma unroll
    for (int r = 0; r < 4; ++r)
        #pragma unroll
        for (int c = 0; c < 8; ++c) acc[r][c] = 0.0f;

    for (int k0 = 0; k0 < K; k0 += 64) {
        #pragma unroll
        for (int i = tid; i < 64 * 64; i += 256) {
            int r = i >> 6, c = i & 63;
            As[r][c] = A[(size_t)(block_row + r) * K + k0 + c];
        }
        #pragma unroll
        for (int i = tid; i < 64 * 128; i += 256) {
            int r = i >> 7, c = i & 127;
            Ws[r][c] = W[(size_t)(k0 + r) * 128 + c];
        }
        __syncthreads();
        #pragma unroll 4
        for (int k = 0; k < 64; ++k) {
            float a[4], w[8];
            #pragma unroll
            for (int r = 0; r < 4; ++r) a[r] = As[ty * 4 + r][k];
            #pragma unroll
            for (int c = 0; c < 8; ++c) w[c] = Ws[k][tx + 16 * c];
            #pragma unroll
            for (int r = 0; r < 4; ++r)
                #pragma unroll
                for (int c = 0; c < 8; ++c) acc[r][c] += a[r] * w[c];
        }
        __syncthreads();
    }
    #pragma unroll
    for (int r = 0; r < 4; ++r)
        #pragma unroll
        for (int c = 0; c < 8; ++c)
            C[(size_t)(block_row + ty * 4 + r) * 128 + tx + 16 * c] = acc[r][c];
}

// ---------------- Edge + self-loop message scatter: out[d] += h[s] * dinv[s]*dinv[d] ----------------
__global__ void k_scatter(const float* __restrict__ h, const int* __restrict__ ei,
                          const float* __restrict__ dinv, float* __restrict__ out) {
    int eid = blockIdx.x * 2 + (threadIdx.x >> 7);   // 2 edges per 256-thread block
    int c = threadIdx.x & 127;
    int s, d;
    if (eid < Bz * Ez) {
        int b = eid >> 10, e = eid & (Ez - 1);
        s = b * Nz + ei[b * 2 * Ez + e];
        d = b * Nz + ei[b * 2 * Ez + Ez + e];
    } else {
        s = d = eid - Bz * Ez;                        // self loop
    }
    float nrm = dinv[s] * dinv[d];
    atomicAdd(out + (size_t)d * GHz + c, h[(size_t)s * GHz + c] * nrm);
}

// ---------------- bias + relu in place over (BN x GH) ----------------
__global__ void k_bias_relu(float* __restrict__ x, const float* __restrict__ bias) {
    int i = blockIdx.x * 256 + threadIdx.x;
    float v = x[i] + bias[i & (GHz - 1)];
    x[i] = v > 0.0f ? v : 0.0f;
}

// ---------------- pooled[b,c] = mean over nodes ----------------
__global__ void k_pool(const float* __restrict__ x2, float* __restrict__ pooled) {
    int b = blockIdx.x;
    int c = threadIdx.x;                  // 128
    float acc = 0.0f;
    for (int n = 0; n < Nz; ++n) acc += x2[(size_t)(b * Nz + n) * GHz + c];
    pooled[b * GHz + c] = acc * (1.0f / Nz);
}

// ---------------- final MLP: out = relu([cls, pooled] @ Wf1 + bf1) @ Wf2 + bf2 ----------------
__global__ void k_mlp(const float* __restrict__ lh, const float* __restrict__ pooled,
                      const float* __restrict__ Wf1, const float* __restrict__ bf1,
                      const float* __restrict__ Wf2, const float* __restrict__ bf2,
                      float* __restrict__ out) {
    int b = blockIdx.x;
    int t = threadIdx.x;                  // 256
    __shared__ float in[Hz + GHz];        // 896
    for (int i = t; i < Hz; i += 256) in[i] = lh[(size_t)b * Sz * Hz + i];   // cls = s=0 row
    if (t < GHz) in[Hz + t] = pooled[b * GHz + t];
    __syncthreads();
    float acc = bf1[t];
    #pragma unroll 4
    for (int k = 0; k < Hz + GHz; ++k) acc += in[k] * Wf1[k * FHz + t];
    float hm = acc > 0.0f ? acc : 0.0f;
    __shared__ float red[256];
    for (int l = 0; l < Lz; ++l) {
        red[t] = hm * Wf2[t * Lz + l];
        __syncthreads();
        for (int s2 = 128; s2 > 0; s2 >>= 1) {
            if (t < s2) red[t] += red[t + s2];
            __syncthreads();
        }
        if (t == 0) out[b * Lz + l] = red[0] + bf2[l];
        __syncthreads();
    }
}

extern "C" void kernel_launch(void* const* d_in, const int* in_sizes, int n_in,
                              void* d_out, int out_size, void* d_ws, size_t ws_size,
                              hipStream_t stream) {
    const float* lh     = (const float*)d_in[0];
    const int*   submap = (const int*)d_in[1];
    const int*   ei     = (const int*)d_in[2];
    // d_in[3] = num_nodes (128), hardcoded
    const float* wr  = (const float*)d_in[4];
    const float* br  = (const float*)d_in[5];
    const float* W1  = (const float*)d_in[6];
    const float* b1  = (const float*)d_in[7];
    const float* W2  = (const float*)d_in[8];
    const float* b2  = (const float*)d_in[9];
    const float* Wf1 = (const float*)d_in[10];
    const float* bf1 = (const float*)d_in[11];
    const float* Wf2 = (const float*)d_in[12];
    const float* bf2 = (const float*)d_in[13];
    float* out = (float*)d_out;

    // workspace layout (floats). Atomic-target zone first (single memset).
    float* ws = (float*)d_ws;
    size_t off = 0;
    float* sums = ws + off; off += (size_t)BNz * Hz;     // 6291456
    float* cnts = ws + off; off += BNz;                  // 8192
    float* dinv = ws + off; off += BNz;                  // 8192 (deg -> rsqrt in place)
    float* x1   = ws + off; off += (size_t)BNz * GHz;    // 1048576
    float* x2   = ws + off; off += (size_t)BNz * GHz;    // 1048576
    size_t zero_floats = off;                            // 8404992 floats = 33.6 MB
    float* h1   = ws + off; off += (size_t)BNz * GHz;
    float* h2   = ws + off; off += (size_t)BNz * GHz;
    float* pooled = ws + off; off += (size_t)Bz * GHz;

    hipMemsetAsync(d_ws, 0, zero_floats * sizeof(float), stream);

    k_gate_scatter<<<Bz * Sz, 256, 0, stream>>>(lh, submap, wr, br, sums, cnts);
    k_deg<<<(Bz * Ez + 255) / 256, 256, 0, stream>>>(ei, dinv);
    k_dinv<<<(BNz + 255) / 256, 256, 0, stream>>>(dinv);
    k_finalize<<<BNz, 256, 0, stream>>>(sums, cnts);

    // GCN layer 1
    k_gemm<Hz><<<BNz / 64, 256, 0, stream>>>(sums, W1, h1);
    k_scatter<<<(Bz * Ez + BNz) / 2, 256, 0, stream>>>(h1, ei, dinv, x1);
    k_bias_relu<<<(BNz * GHz) / 256, 256, 0, stream>>>(x1, b1);

    // GCN layer 2
    k_gemm<GHz><<<BNz / 64, 256, 0, stream>>>(x1, W2, h2);
    k_scatter<<<(Bz * Ez + BNz) / 2, 256, 0, stream>>>(h2, ei, dinv, x2);
    k_bias_relu<<<(BNz * GHz) / 256, 256, 0, stream>>>(x2, b2);

    k_pool<<<Bz, 128, 0, stream>>>(x2, pooled);
    k_mlp<<<Bz, 256, 0, stream>>>(lh, pooled, Wf1, bf1, Wf2, bf2, out);
}

// Round 2
// 564.157 us; speedup vs baseline: 1.0910x; 1.0910x over previous
//
#include <hip/hip_runtime.h>
#include <hip/hip_bf16.h>
#include <math.h>

#define Bz 64
#define Sz 512
#define Hz 768
#define Nz 128
#define Ez 1024
#define GHz 128
#define FHz 256
#define Lz 2
#define BNz (Bz * Nz)          // 8192

// ---------------- Kernel 1: gate = sigmoid(lh . wr + br); atomic scatter of gated rows ----------------
__global__ void k_gate_scatter(const float* __restrict__ lh, const int* __restrict__ submap,
                               const float* __restrict__ wr, const float* __restrict__ br,
                               float* __restrict__ sums, float* __restrict__ cnts) {
    int row = blockIdx.x;                 // 0 .. B*S-1
    int tid = threadIdx.x;                // 256 threads
    const float* x = lh + (size_t)row * Hz;
    float v0 = x[tid], v1 = x[tid + 256], v2 = x[tid + 512];
    float p = v0 * wr[tid] + v1 * wr[tid + 256] + v2 * wr[tid + 512];
    #pragma unroll
    for (int off = 32; off > 0; off >>= 1) p += __shfl_down(p, off);
    __shared__ float wsum[4];
    __shared__ float gate_s;
    int lane = tid & 63, wid = tid >> 6;
    if (lane == 0) wsum[wid] = p;
    __syncthreads();
    if (tid == 0) {
        float z = wsum[0] + wsum[1] + wsum[2] + wsum[3] + br[0];
        gate_s = 1.0f / (1.0f + expf(-z));
    }
    __syncthreads();
    float g = gate_s;
    int b = row >> 9;                     // row / S
    int seg = b * Nz + submap[row];
    float* dstp = sums + (size_t)seg * Hz;
    atomicAdd(dstp + tid,       v0 * g);
    atomicAdd(dstp + tid + 256, v1 * g);
    atomicAdd(dstp + tid + 512, v2 * g);
    if (tid == 0) atomicAdd(cnts + seg, 1.0f);
}

// ---------------- Kernel 2: degree from edges (dst side) ----------------
__global__ void k_deg(const int* __restrict__ ei, float* __restrict__ deg) {
    int idx = blockIdx.x * 256 + threadIdx.x;
    if (idx >= Bz * Ez) return;
    int b = idx >> 10;
    int e = idx & (Ez - 1);
    int dst = ei[b * 2 * Ez + Ez + e];
    atomicAdd(deg + b * Nz + dst, 1.0f);
}

// ---------------- Kernel 3: dinv = rsqrt(deg_edges + 1 [self loop]) ----------------
__global__ void k_dinv(float* __restrict__ deg) {
    int i = blockIdx.x * 256 + threadIdx.x;
    if (i < BNz) deg[i] = rsqrtf(deg[i] + 1.0f);
}

// ---------------- Kernel 4: node_feats = sums / max(cnts,1)  (in place) ----------------
__global__ void k_finalize(float* __restrict__ sums, const float* __restrict__ cnts) {
    int row = blockIdx.x;
    int tid = threadIdx.x;
    float inv = 1.0f / fmaxf(cnts[row], 1.0f);
    float* p = sums + (size_t)row * Hz;
    p[tid] *= inv; p[tid + 256] *= inv; p[tid + 512] *= inv;
}

// ---------------- GEMM: C(BN x 128) += A(BN x K[chunk]) @ W(K x 128), K-split across blockIdx.y ----------------
// 64x128 tile, 4x8 per thread, contiguous per-thread cols -> ds_read_b128 W fragments.
// C must be pre-zeroed (atomic accumulation across K-chunks).
template <int K, int KC>
__global__ void k_gemm(const float* __restrict__ A, const float* __restrict__ W,
                       float* __restrict__ C) {
    __shared__ float As[64][65];          // +1 pad
    __shared__ float Ws[64][128];
    int block_row = blockIdx.x * 64;
    int chunk = blockIdx.y;
    int tid = threadIdx.x;                // 256
    int tx = tid & 15;                    // cols tx*8 .. tx*8+7 (contiguous)
    int ty = tid >> 4;                    // rows ty*4 .. ty*4+3
    float acc[4][8];
    #pragma unroll
    for (int r = 0; r < 4; ++r)
        #pragma unroll
        for (int c = 0; c < 8; ++c) acc[r][c] = 0.0f;

    for (int kk = 0; kk < KC; kk += 64) {
        int k0 = chunk * KC + kk;
        #pragma unroll
        for (int i = tid; i < 64 * 64; i += 256) {
            int r = i >> 6, c = i & 63;
            As[r][c] = A[(size_t)(block_row + r) * K + k0 + c];
        }
        #pragma unroll
        for (int i = tid; i < 64 * 128; i += 256) {
            int r = i >> 7, c = i & 127;
            Ws[r][c] = W[(size_t)(k0 + r) * 128 + c];
        }
        __syncthreads();
        #pragma unroll 8
        for (int k = 0; k < 64; ++k) {
            float a[4];
            #pragma unroll
            for (int r = 0; r < 4; ++r) a[r] = As[ty * 4 + r][k];
            float4 w0 = *(const float4*)&Ws[k][tx * 8];
            float4 w1 = *(const float4*)&Ws[k][tx * 8 + 4];
            float w[8] = {w0.x, w0.y, w0.z, w0.w, w1.x, w1.y, w1.z, w1.w};
            #pragma unroll
            for (int r = 0; r < 4; ++r)
                #pragma unroll
                for (int c = 0; c < 8; ++c) acc[r][c] += a[r] * w[c];
        }
        __syncthreads();
    }
    #pragma unroll
    for (int r = 0; r < 4; ++r)
        #pragma unroll
        for (int c = 0; c < 8; ++c)
            atomicAdd(&C[(size_t)(block_row + ty * 4 + r) * 128 + tx * 8 + c], acc[r][c]);
}

// ---------------- Edge + self-loop message scatter: out[d] += h[s] * dinv[s]*dinv[d] ----------------
__global__ void k_scatter(const float* __restrict__ h, const int* __restrict__ ei,
                          const float* __restrict__ dinv, float* __restrict__ out) {
    int eid = blockIdx.x * 2 + (threadIdx.x >> 7);
    int c = threadIdx.x & 127;
    int s, d;
    if (eid < Bz * Ez) {
        int b = eid >> 10, e = eid & (Ez - 1);
        s = b * Nz + ei[b * 2 * Ez + e];
        d = b * Nz + ei[b * 2 * Ez + Ez + e];
    } else {
        s = d = eid - Bz * Ez;            // self loop
    }
    float nrm = dinv[s] * dinv[d];
    atomicAdd(out + (size_t)d * GHz + c, h[(size_t)s * GHz + c] * nrm);
}

// ---------------- bias + relu in place over (BN x GH) ----------------
__global__ void k_bias_relu(float* __restrict__ x, const float* __restrict__ bias) {
    int i = blockIdx.x * 256 + threadIdx.x;
    float v = x[i] + bias[i & (GHz - 1)];
    x[i] = v > 0.0f ? v : 0.0f;
}

// ---------------- bias + relu + fused mean-pool (layer 2) ----------------
// block = 8 rows (1024 elems); pooled must be pre-zeroed.
__global__ void k_bias_relu_pool(float* __restrict__ x, const float* __restrict__ bias,
                                 float* __restrict__ pooled) {
    __shared__ float sx[8][128];
    int blk = blockIdx.x;                 // 1024 blocks
    int t = threadIdx.x;                  // 256, 4 elems each
    size_t base = (size_t)blk * 1024 + t * 4;
    float4 v = *(float4*)&x[base];
    int col = (t * 4) & 127;
    int row = t >> 5;
    v.x = fmaxf(v.x + bias[col], 0.0f);
    v.y = fmaxf(v.y + bias[col + 1], 0.0f);
    v.z = fmaxf(v.z + bias[col + 2], 0.0f);
    v.w = fmaxf(v.w + bias[col + 3], 0.0f);
    *(float4*)&x[base] = v;
    sx[row][col] = v.x; sx[row][col + 1] = v.y; sx[row][col + 2] = v.z; sx[row][col + 3] = v.w;
    __syncthreads();
    if (t < 128) {
        float s = 0.0f;
        #pragma unroll
        for (int r = 0; r < 8; ++r) s += sx[r][t];
        atomicAdd(&pooled[(blk >> 4) * 128 + t], s * (1.0f / Nz));
    }
}

// ---------------- MLP stage 1: hmat[b][col] = relu([cls,pooled] . Wf1[:,col] + bf1[col]) ----------------
// grid (4, 64): blockIdx.x = col quarter, blockIdx.y = b. 256 threads = 64 cols x 4 k-chunks.
__global__ void k_mlp1(const float* __restrict__ lh, const float* __restrict__ pooled,
                       const float* __restrict__ Wf1, const float* __restrict__ bf1,
                       float* __restrict__ hmat) {
    int b = blockIdx.y, cq = blockIdx.x;
    int t = threadIdx.x;
    __shared__ float in[Hz + GHz];        // 896
    for (int i = t; i < Hz; i += 256) in[i] = lh[(size_t)b * Sz * Hz + i];
    if (t < GHz) in[Hz + t] = pooled[b * GHz + t];
    __syncthreads();
    int col = cq * 64 + (t & 63);
    int kc = t >> 6;                      // 0..3, k-chunks of 224
    float acc = 0.0f;
    int kend = kc * 224 + 224;
    #pragma unroll 4
    for (int k = kc * 224; k < kend; ++k) acc += in[k] * Wf1[(size_t)k * FHz + col];
    __shared__ float red[4][64];
    red[kc][t & 63] = acc;
    __syncthreads();
    if (kc == 0) {
        float s = red[0][t] + red[1][t] + red[2][t] + red[3][t] + bf1[col];
        hmat[b * FHz + col] = s > 0.0f ? s : 0.0f;
    }
}

// ---------------- MLP stage 2: out = hmat @ Wf2 + bf2 ----------------
__global__ void k_mlp2(const float* __restrict__ hmat, const float* __restrict__ Wf2,
                       const float* __restrict__ bf2, float* __restrict__ out) {
    int b = blockIdx.x;
    int t = threadIdx.x;                  // 256
    float hv = hmat[b * FHz + t];
    __shared__ float red[256];
    for (int l = 0; l < Lz; ++l) {
        red[t] = hv * Wf2[t * Lz + l];
        __syncthreads();
        for (int s2 = 128; s2 > 0; s2 >>= 1) {
            if (t < s2) red[t] += red[t + s2];
            __syncthreads();
        }
        if (t == 0) out[b * Lz + l] = red[0] + bf2[l];
        __syncthreads();
    }
}

extern "C" void kernel_launch(void* const* d_in, const int* in_sizes, int n_in,
                              void* d_out, int out_size, void* d_ws, size_t ws_size,
                              hipStream_t stream) {
    const float* lh     = (const float*)d_in[0];
    const int*   submap = (const int*)d_in[1];
    const int*   ei     = (const int*)d_in[2];
    const float* wr  = (const float*)d_in[4];
    const float* br  = (const float*)d_in[5];
    const float* W1  = (const float*)d_in[6];
    const float* b1  = (const float*)d_in[7];
    const float* W2  = (const float*)d_in[8];
    const float* b2  = (const float*)d_in[9];
    const float* Wf1 = (const float*)d_in[10];
    const float* bf1 = (const float*)d_in[11];
    const float* Wf2 = (const float*)d_in[12];
    const float* bf2 = (const float*)d_in[13];
    float* out = (float*)d_out;

    // workspace layout (floats) — entire zone zeroed once (atomic targets).
    float* ws = (float*)d_ws;
    size_t off = 0;
    float* sums   = ws + off; off += (size_t)BNz * Hz;   // 6291456 (dead after gemm1; hmat aliases it)
    float* cnts   = ws + off; off += BNz;
    float* dinv   = ws + off; off += BNz;                // deg -> rsqrt in place
    float* x1     = ws + off; off += (size_t)BNz * GHz;
    float* x2     = ws + off; off += (size_t)BNz * GHz;
    float* pooled = ws + off; off += Bz * GHz;
    float* h1     = ws + off; off += (size_t)BNz * GHz;
    float* h2     = ws + off; off += (size_t)BNz * GHz;
    size_t zero_floats = off;                            // 10510336 floats = 42.0 MB
    float* hmat = sums;                                  // alias (64*256 floats)

    hipMemsetAsync(d_ws, 0, zero_floats * sizeof(float), stream);

    k_gate_scatter<<<Bz * Sz, 256, 0, stream>>>(lh, submap, wr, br, sums, cnts);
    k_deg<<<(Bz * Ez + 255) / 256, 256, 0, stream>>>(ei, dinv);
    k_dinv<<<(BNz + 255) / 256, 256, 0, stream>>>(dinv);
    k_finalize<<<BNz, 256, 0, stream>>>(sums, cnts);

    // GCN layer 1: K=768 split into 4 chunks of 192 -> 512 blocks
    k_gemm<Hz, 192><<<dim3(BNz / 64, 4), 256, 0, stream>>>(sums, W1, h1);
    k_scatter<<<(Bz * Ez + BNz) / 2, 256, 0, stream>>>(h1, ei, dinv, x1);
    k_bias_relu<<<(BNz * GHz) / 256, 256, 0, stream>>>(x1, b1);

    // GCN layer 2: K=128 split into 2 chunks of 64 -> 256 blocks
    k_gemm<GHz, 64><<<dim3(BNz / 64, 2), 256, 0, stream>>>(x1, W2, h2);
    k_scatter<<<(Bz * Ez + BNz) / 2, 256, 0, stream>>>(h2, ei, dinv, x2);
    k_bias_relu_pool<<<(BNz * GHz) / 1024, 256, 0, stream>>>(x2, b2, pooled);

    k_mlp1<<<dim3(4, Bz), 256, 0, stream>>>(lh, pooled, Wf1, bf1, hmat);
    k_mlp2<<<Bz, 256, 0, stream>>>(hmat, Wf2, bf2, out);
}

// Round 4
// 300.251 us; speedup vs baseline: 2.0500x; 1.8790x over previous
//
#include <hip/hip_runtime.h>
#include <hip/hip_bf16.h>
#include <math.h>

#define Bz 64
#define Sz 512
#define Hz 768
#define Nz 128
#define Ez 1024
#define GHz 128
#define FHz 256
#define Lz 2
#define BNz (Bz * Nz)          // 8192
#define CPSTRIDE (BNz * GHz)   // 1048576 floats per K-chunk partial
#define ASTRIDE 68             // As row stride: 68*4=272 B keeps float4 alignment; (4r+k)%32 -> 2-way bank alias (free)

// ============ node gather: per (b,n) block gathers its rows, computes gate in-block ============
// nf[b*N+n][:] = (sum_{s: submap[b,s]==n} sigmoid(lh[b,s].wr + br) * lh[b,s]) / max(cnt,1)
__global__ void k_node_gather(const float* __restrict__ lh, const int* __restrict__ submap,
                              const float* __restrict__ wr, const float* __restrict__ br,
                              float* __restrict__ nf) {
    int n = blockIdx.x, b = blockIdx.y;
    int t = threadIdx.x;                  // 256
    __shared__ int list[Sz];
    __shared__ int lcnt;
    __shared__ float wsum[4];
    __shared__ float gbuf;
    float wr0 = wr[t], wr1 = wr[t + 256], wr2 = wr[t + 512];
    if (t == 0) lcnt = 0;
    __syncthreads();
    int s0 = submap[b * Sz + t];
    int s1 = submap[b * Sz + 256 + t];
    if (s0 == n) { int p = atomicAdd(&lcnt, 1); list[p] = t; }        // LDS atomics only
    if (s1 == n) { int p = atomicAdd(&lcnt, 1); list[p] = 256 + t; }
    __syncthreads();
    int cnt = lcnt;
    int lane = t & 63, wid = t >> 6;
    float a0 = 0.0f, a1 = 0.0f, a2 = 0.0f;
    for (int i = 0; i < cnt; ++i) {
        const float* x = lh + (size_t)(b * Sz + list[i]) * Hz;
        float v0 = x[t], v1 = x[t + 256], v2 = x[t + 512];
        float p = v0 * wr0 + v1 * wr1 + v2 * wr2;
        #pragma unroll
        for (int off = 32; off > 0; off >>= 1) p += __shfl_down(p, off);
        if (lane == 0) wsum[wid] = p;
        __syncthreads();
        if (t == 0) {
            float z = wsum[0] + wsum[1] + wsum[2] + wsum[3] + br[0];
            gbuf = 1.0f / (1.0f + expf(-z));
        }
        __syncthreads();
        float g = gbuf;
        a0 += g * v0; a1 += g * v1; a2 += g * v2;
    }
    float invc = 1.0f / fmaxf((float)cnt, 1.0f);
    float* o = nf + (size_t)(b * Nz + n) * Hz;
    o[t] = a0 * invc; o[t + 256] = a1 * invc; o[t + 512] = a2 * invc;
}

// ============ degree via per-batch LDS histogram; dinv = rsqrt(deg+1) ============
__global__ void k_deg_dinv(const int* __restrict__ ei, float* __restrict__ dinv) {
    int b = blockIdx.x;
    int t = threadIdx.x;                  // 256
    __shared__ int hist[Nz];
    if (t < Nz) hist[t] = 0;
    __syncthreads();
    #pragma unroll
    for (int j = 0; j < 4; ++j) {
        int d = ei[b * 2 * Ez + Ez + t + 256 * j];
        atomicAdd(&hist[d], 1);
    }
    __syncthreads();
    if (t < Nz) dinv[b * Nz + t] = rsqrtf((float)hist[t] + 1.0f);
}

// ============ GEMM: Cp[chunk] = A(BN x K[chunk slice]) @ W(K x 128), plain stores ============
// 64x128 tile, 4 rows x 8 cols per thread, K staged in 64-wide sub-iters.
// Staging is fully vectorized: As = 1024 float4 (4 iters), Ws = 2048 float4 (8 iters).
template <int K, int KC>
__global__ void k_gemm(const float* __restrict__ A, const float* __restrict__ W,
                       float* __restrict__ Cp) {
    __shared__ __align__(16) float As[64 * ASTRIDE];
    __shared__ __align__(16) float Ws[64 * 128];
    int block_row = blockIdx.x * 64;
    int k_base = blockIdx.y * KC;
    int tid = threadIdx.x;                // 256
    int tx = tid & 15;                    // cols tx*8 .. +7
    int ty = tid >> 4;                    // rows ty*4 .. +3
    float acc[4][8];
    #pragma unroll
    for (int r = 0; r < 4; ++r)
        #pragma unroll
        for (int c = 0; c < 8; ++c) acc[r][c] = 0.0f;

    for (int kk = 0; kk < KC; kk += 64) {
        int k0 = k_base + kk;
        // A tile: 64 rows x 64 k = 1024 float4
        #pragma unroll
        for (int j = 0; j < 4; ++j) {
            int idx = tid + 256 * j;
            int r = idx >> 4, c4 = idx & 15;         // r 0..63, c4 0..15
            float4 v = *(const float4*)&A[(size_t)(block_row + r) * K + k0 + c4 * 4];
            *(float4*)&As[r * ASTRIDE + c4 * 4] = v;
        }
        // W tile: 64 k x 128 cols = 2048 float4
        #pragma unroll
        for (int j = 0; j < 8; ++j) {
            int idx = tid + 256 * j;
            int r = idx >> 5, c4 = idx & 31;         // r 0..63, c4 0..31
            float4 v = *(const float4*)&W[(size_t)(k0 + r) * 128 + c4 * 4];
            *(float4*)&Ws[r * 128 + c4 * 4] = v;
        }
        __syncthreads();
        #pragma unroll 8
        for (int k = 0; k < 64; ++k) {
            float a0 = As[(ty * 4 + 0) * ASTRIDE + k];
            float a1 = As[(ty * 4 + 1) * ASTRIDE + k];
            float a2 = As[(ty * 4 + 2) * ASTRIDE + k];
            float a3 = As[(ty * 4 + 3) * ASTRIDE + k];
            float4 w0 = *(const float4*)&Ws[k * 128 + tx * 8];
            float4 w1 = *(const float4*)&Ws[k * 128 + tx * 8 + 4];
            float w[8] = {w0.x, w0.y, w0.z, w0.w, w1.x, w1.y, w1.z, w1.w};
            #pragma unroll
            for (int c = 0; c < 8; ++c) {
                acc[0][c] += a0 * w[c];
                acc[1][c] += a1 * w[c];
                acc[2][c] += a2 * w[c];
                acc[3][c] += a3 * w[c];
            }
        }
        __syncthreads();
    }
    float* Cb = Cp + (size_t)blockIdx.y * CPSTRIDE;
    #pragma unroll
    for (int r = 0; r < 4; ++r) {
        size_t o = (size_t)(block_row + ty * 4 + r) * 128 + tx * 8;
        *(float4*)&Cb[o]     = make_float4(acc[r][0], acc[r][1], acc[r][2], acc[r][3]);
        *(float4*)&Cb[o + 4] = make_float4(acc[r][4], acc[r][5], acc[r][6], acc[r][7]);
    }
}

// ============ reduce K-chunk partials: h = sum_c Cp[c] ============
template <int NCH>
__global__ void k_reduce(const float* __restrict__ Cp, float* __restrict__ h) {
    size_t i = ((size_t)blockIdx.x * 256 + threadIdx.x) * 4;
    float4 s = *(const float4*)&Cp[i];
    #pragma unroll
    for (int c = 1; c < NCH; ++c) {
        float4 v = *(const float4*)&Cp[(size_t)c * CPSTRIDE + i];
        s.x += v.x; s.y += v.y; s.z += v.z; s.w += v.w;
    }
    *(float4*)&h[i] = s;
}

// ============ edge gather per (b,dst): out = relu(sum_in h[src]*dinv[s]*dinv[d] + self + bias) ============
__global__ void k_edge_gather(const float* __restrict__ h, const int* __restrict__ ei,
                              const float* __restrict__ dinv, const float* __restrict__ bias,
                              float* __restrict__ out) {
    int d = blockIdx.x, b = blockIdx.y;
    int t = threadIdx.x;                  // 128
    __shared__ int list[Ez];
    __shared__ int lcnt;
    if (t == 0) lcnt = 0;
    __syncthreads();
    const int* srcp = ei + b * 2 * Ez;
    const int* dstp = srcp + Ez;
    #pragma unroll
    for (int j = 0; j < 8; ++j) {
        int e = t + 128 * j;
        if (dstp[e] == d) { int p = atomicAdd(&lcnt, 1); list[p] = e; }
    }
    __syncthreads();
    int cnt = lcnt;
    float dd = dinv[b * Nz + d];
    float acc = h[(size_t)(b * Nz + d) * GHz + t] * dd * dd;   // self loop
    for (int i = 0; i < cnt; ++i) {
        int s = srcp[list[i]];
        float nrm = dinv[b * Nz + s] * dd;
        acc += h[(size_t)(b * Nz + s) * GHz + t] * nrm;
    }
    out[(size_t)(b * Nz + d) * GHz + t] = fmaxf(acc + bias[t], 0.0f);
}

// ============ pooled[b] = mean over nodes of x2[b] ============
__global__ void k_pool(const float* __restrict__ x2, float* __restrict__ pooled) {
    int b = blockIdx.x;
    int t = threadIdx.x;                  // 256
    int col = t & 127, half = t >> 7;
    float s = 0.0f;
    for (int r = 0; r < 64; ++r)
        s += x2[(size_t)(b * Nz + half * 64 + r) * GHz + col];
    __shared__ float buf[2][128];
    buf[half][col] = s;
    __syncthreads();
    if (t < 128) pooled[b * GHz + t] = (buf[0][t] + buf[1][t]) * (1.0f / Nz);
}

// ============ MLP stage 1 ============
__global__ void k_mlp1(const float* __restrict__ lh, const float* __restrict__ pooled,
                       const float* __restrict__ Wf1, const float* __restrict__ bf1,
                       float* __restrict__ hmat) {
    int b = blockIdx.y, cq = blockIdx.x;
    int t = threadIdx.x;
    __shared__ float in[Hz + GHz];        // 896
    for (int i = t; i < Hz; i += 256) in[i] = lh[(size_t)b * Sz * Hz + i];  // cls row s=0
    if (t < GHz) in[Hz + t] = pooled[b * GHz + t];
    __syncthreads();
    int col = cq * 64 + (t & 63);
    int kc = t >> 6;                      // 4 k-chunks of 224
    float acc = 0.0f;
    int kend = kc * 224 + 224;
    #pragma unroll 4
    for (int k = kc * 224; k < kend; ++k) acc += in[k] * Wf1[(size_t)k * FHz + col];
    __shared__ float red[4][64];
    red[kc][t & 63] = acc;
    __syncthreads();
    if (kc == 0) {
        float s = red[0][t] + red[1][t] + red[2][t] + red[3][t] + bf1[col];
        hmat[b * FHz + col] = s > 0.0f ? s : 0.0f;
    }
}

// ============ MLP stage 2 ============
__global__ void k_mlp2(const float* __restrict__ hmat, const float* __restrict__ Wf2,
                       const float* __restrict__ bf2, float* __restrict__ out) {
    int b = blockIdx.x;
    int t = threadIdx.x;                  // 256
    float hv = hmat[b * FHz + t];
    __shared__ float red[256];
    for (int l = 0; l < Lz; ++l) {
        red[t] = hv * Wf2[t * Lz + l];
        __syncthreads();
        for (int s2 = 128; s2 > 0; s2 >>= 1) {
            if (t < s2) red[t] += red[t + s2];
            __syncthreads();
        }
        if (t == 0) out[b * Lz + l] = red[0] + bf2[l];
        __syncthreads();
    }
}

extern "C" void kernel_launch(void* const* d_in, const int* in_sizes, int n_in,
                              void* d_out, int out_size, void* d_ws, size_t ws_size,
                              hipStream_t stream) {
    const float* lh     = (const float*)d_in[0];
    const int*   submap = (const int*)d_in[1];
    const int*   ei     = (const int*)d_in[2];
    const float* wr  = (const float*)d_in[4];
    const float* br  = (const float*)d_in[5];
    const float* W1  = (const float*)d_in[6];
    const float* b1  = (const float*)d_in[7];
    const float* W2  = (const float*)d_in[8];
    const float* b2  = (const float*)d_in[9];
    const float* Wf1 = (const float*)d_in[10];
    const float* bf1 = (const float*)d_in[11];
    const float* Wf2 = (const float*)d_in[12];
    const float* bf2 = (const float*)d_in[13];
    float* out = (float*)d_out;

    // ---- workspace layout (floats), heavy aliasing; total 41.97 MB ----
    // nf[6291456] | dinv[8192] | Cp[4*1048576]
    // aliases into nf (dead after gemm1): h1@0, x1@1M, h2@2M, x2@3M, pooled@4M, hmat@4M+8K
    float* ws = (float*)d_ws;
    float* nf   = ws;
    float* dinv = ws + 6291456;
    float* Cp   = ws + 6299648;
    float* h1     = nf;
    float* x1     = nf + 1 * CPSTRIDE;
    float* h2     = nf + 2 * CPSTRIDE;
    float* x2     = nf + 3 * CPSTRIDE;
    float* pooled = nf + 4 * CPSTRIDE;
    float* hmat   = nf + 4 * CPSTRIDE + 8192;

    // no memsets: every buffer is fully written before it is read; no global atomics anywhere
    k_node_gather<<<dim3(Nz, Bz), 256, 0, stream>>>(lh, submap, wr, br, nf);
    k_deg_dinv<<<Bz, 256, 0, stream>>>(ei, dinv);

    // GCN layer 1: K=768, 4 chunks of 192 -> 512 blocks, partials + reduce
    k_gemm<Hz, 192><<<dim3(BNz / 64, 4), 256, 0, stream>>>(nf, W1, Cp);
    k_reduce<4><<<CPSTRIDE / 1024, 256, 0, stream>>>(Cp, h1);
    k_edge_gather<<<dim3(Nz, Bz), 128, 0, stream>>>(h1, ei, dinv, b1, x1);

    // GCN layer 2: K=128, 2 chunks of 64 -> 256 blocks
    k_gemm<GHz, 64><<<dim3(BNz / 64, 2), 256, 0, stream>>>(x1, W2, Cp);
    k_reduce<2><<<CPSTRIDE / 1024, 256, 0, stream>>>(Cp, h2);
    k_edge_gather<<<dim3(Nz, Bz), 128, 0, stream>>>(h2, ei, dinv, b2, x2);

    k_pool<<<Bz, 256, 0, stream>>>(x2, pooled);
    k_mlp1<<<dim3(4, Bz), 256, 0, stream>>>(lh, pooled, Wf1, bf1, hmat);
    k_mlp2<<<Bz, 256, 0, stream>>>(hmat, Wf2, bf2, out);
}